// Round 5
// baseline (618.506 us; speedup 1.0000x reference)
//
#include <hip/hip_runtime.h>

typedef unsigned short u16;
typedef __attribute__((ext_vector_type(8))) short short8;
typedef __attribute__((ext_vector_type(4))) float f32x4;
typedef __attribute__((ext_vector_type(8))) __bf16 bf16x8;

__device__ __forceinline__ float b2f(u16 u) {
  unsigned int i = ((unsigned int)u) << 16;
  return __builtin_bit_cast(float, i);
}
__device__ __forceinline__ u16 f2b(float f) {
  unsigned int i = __builtin_bit_cast(unsigned int, f);
  i += 0x7fffu + ((i >> 16) & 1u);   // RNE
  return (u16)(i >> 16);
}

// ---------------------------------------------------------------------------
// K0: fp32 -> bf16 conversion. (unchanged)
// ---------------------------------------------------------------------------
__global__ __launch_bounds__(256) void cvt_bf16(const float* __restrict__ in,
                                                u16* __restrict__ out, int n8) {
  int i = blockIdx.x * 256 + threadIdx.x;
  if (i >= n8) return;
  f32x4 v0 = *(const f32x4*)(in + (size_t)i * 8);
  f32x4 v1 = *(const f32x4*)(in + (size_t)i * 8 + 4);
  short8 o;
  o[0] = (short)f2b(v0.x); o[1] = (short)f2b(v0.y);
  o[2] = (short)f2b(v0.z); o[3] = (short)f2b(v0.w);
  o[4] = (short)f2b(v1.x); o[5] = (short)f2b(v1.y);
  o[6] = (short)f2b(v1.z); o[7] = (short)f2b(v1.w);
  *(short8*)(out + (size_t)i * 8) = o;
}

// ---------------------------------------------------------------------------
// K1: KV projection bf16 MFMA GEMM + T1 XCD swizzle.
// CHANGED: transposed accumulation — accT[n][m] = mfma(b[n], a[m], .) makes
// D-rows = f (features), D-cols = s (tokens). Each fragment's j=0..3 are then
// 4 CONSECUTIVE d in the same KV row -> pack 4 bf16 into one 8B store.
// Epilogue: 64 scalar 2B stores/thread -> 16 dwordx2 stores/thread.
// ---------------------------------------------------------------------------
__global__ __launch_bounds__(256) void kv_gemm_mfma(const u16* __restrict__ A,
                                                    const u16* __restrict__ B,
                                                    u16* __restrict__ KV, int nb) {
  __shared__ u16 As[128 * 32];
  __shared__ u16 Bs[128 * 32];
  const int tid = threadIdx.x;
  const int lane = tid & 63;
  const int w = tid >> 6;
  const int wr = w >> 1, wc = w & 1;
  const int fr = lane & 15;
  const int fq = lane >> 4;

  const int bid0 = blockIdx.x;
  const int cpx = gridDim.x >> 3;
  const int bid = (bid0 & 7) * cpx + (bid0 >> 3);

  const int nt = bid % 12, mt = bid / 12;
  const int m0 = mt * 128, n0 = nt * 128;

  f32x4 accT[4][4] = {};   // [n][m]: rows = f-block, cols = s-block

  for (int k0 = 0; k0 < 768; k0 += 32) {
#pragma unroll
    for (int i = 0; i < 2; ++i) {
      int c = w * 128 + i * 64 + lane;
      int row = c >> 2, q = c & 3;
      const u16* ga = A + (size_t)(m0 + row) * 768 + k0 + q * 8;
      const u16* gb = B + (size_t)(n0 + row) * 768 + k0 + q * 8;
      __builtin_amdgcn_global_load_lds(
          (const __attribute__((address_space(1))) void*)ga,
          (__attribute__((address_space(3))) void*)(As + (size_t)(w * 128 + i * 64) * 8),
          16, 0, 0);
      __builtin_amdgcn_global_load_lds(
          (const __attribute__((address_space(1))) void*)gb,
          (__attribute__((address_space(3))) void*)(Bs + (size_t)(w * 128 + i * 64) * 8),
          16, 0, 0);
    }
    __syncthreads();

    bf16x8 a[4], b[4];
#pragma unroll
    for (int m = 0; m < 4; ++m)
      a[m] = *(const bf16x8*)(As + (size_t)(wr * 64 + m * 16 + fr) * 32 + fq * 8);
#pragma unroll
    for (int n = 0; n < 4; ++n)
      b[n] = *(const bf16x8*)(Bs + (size_t)(wc * 64 + n * 16 + fr) * 32 + fq * 8);
#pragma unroll
    for (int n = 0; n < 4; ++n)
#pragma unroll
      for (int m = 0; m < 4; ++m)
        accT[n][m] = __builtin_amdgcn_mfma_f32_16x16x32_bf16(b[n], a[m], accT[n][m], 0, 0, 0);
    __syncthreads();
  }

  // Epilogue (transposed): lane holds f = n0+wc*64+n*16+fq*4+j (j=0..3
  // consecutive, never crossing a 4-aligned h/kvsel/d-64 boundary),
  // s = (m0&8191)+wr*64+m*16+fr.
  const int bl = m0 >> 13;
  const int s_ = (m0 & 8191) + wr * 64 + fr;
#pragma unroll
  for (int n = 0; n < 4; ++n) {
    int f0 = n0 + wc * 64 + n * 16 + fq * 4;
    int kvsel = f0 >= 768 ? 1 : 0;
    int h = (f0 >> 6) - kvsel * 12;
    int d0 = f0 & 63;
    u16* outp = KV + ((size_t)(kvsel * nb + bl) * 12 + h) * (8192 * 64) + d0;
#pragma unroll
    for (int m = 0; m < 4; ++m) {
      int s = s_ + m * 16;
      union { u16 q[4]; unsigned long long u; } pk;
      pk.q[0] = f2b(accT[n][m][0]);
      pk.q[1] = f2b(accT[n][m][1]);
      pk.q[2] = f2b(accT[n][m][2]);
      pk.q[3] = f2b(accT[n][m][3]);
      *(unsigned long long*)(outp + (size_t)s * 64) = pk.u;
    }
  }
}

// ---------------------------------------------------------------------------
// K2: Q projection (fp32), scale 0.125 folded in. (unchanged)
// ---------------------------------------------------------------------------
__global__ __launch_bounds__(256) void q_proj(const float* __restrict__ X,
                                              const float* __restrict__ Wq,
                                              float* __restrict__ Q) {
  __shared__ float xs[768];
  const int bid = blockIdx.x;
  const int rrow = bid / 3, cg = bid % 3;
  const int b = rrow >> 2, s = rrow & 3;
  const float* xrow = X + ((size_t)b * 8192 + s) * 768;
  const int t = threadIdx.x;
  if (t < 192) *(f32x4*)&xs[t * 4] = *(const f32x4*)(xrow + t * 4);
  __syncthreads();
  const int c = cg * 256 + t;
  const float* wrow = Wq + (size_t)c * 768;
  float acc = 0.f;
#pragma unroll 8
  for (int jj = 0; jj < 192; ++jj) {
    f32x4 v = *(const f32x4*)(wrow + jj * 4);
    acc += v.x * xs[jj * 4] + v.y * xs[jj * 4 + 1] + v.z * xs[jj * 4 + 2] +
           v.w * xs[jj * 4 + 3];
  }
  Q[(size_t)rrow * 768 + c] = acc * 0.125f;
}

// ---------------------------------------------------------------------------
// K3a: split-S attention partials. (unchanged from round 3)
// ---------------------------------------------------------------------------
#define CHUNK 256
#define NSCH 32

__global__ __launch_bounds__(256) void attn_part(const u16* __restrict__ KV,
                                                 const float* __restrict__ Q,
                                                 float* __restrict__ Mp,
                                                 float* __restrict__ Lp,
                                                 float* __restrict__ Op,
                                                 int b0, int nb) {
  __shared__ float qsh[4][64];
  __shared__ float sc[4][CHUNK];
  const int tid = threadIdx.x;
  const int bid = blockIdx.x;
  const int ch = bid % NSCH;
  const int rem = bid / NSCH;
  const int h = rem % 12, bl = rem / 12;
  const int b = b0 + bl;

  qsh[tid >> 6][tid & 63] = Q[(size_t)(b * 4 + (tid >> 6)) * 768 + h * 64 + (tid & 63)];
  __syncthreads();

  const u16* Kb = KV + (size_t)(bl * 12 + h) * (8192 * 64) + (size_t)ch * CHUNK * 64;
  const u16* Vb = KV + (size_t)((nb + bl) * 12 + h) * (8192 * 64) + (size_t)ch * CHUNK * 64;

  const int wv = tid >> 6;           // wave 0..3
  const int lane = tid & 63;
  const int ys = lane >> 3, dc = lane & 7;

  float qr[4][8];
#pragma unroll
  for (int x = 0; x < 4; ++x) {
    f32x4 lo = *(const f32x4*)&qsh[x][dc * 8];
    f32x4 hi = *(const f32x4*)&qsh[x][dc * 8 + 4];
    qr[x][0] = lo.x; qr[x][1] = lo.y; qr[x][2] = lo.z; qr[x][3] = lo.w;
    qr[x][4] = hi.x; qr[x][5] = hi.y; qr[x][6] = hi.z; qr[x][7] = hi.w;
  }

#pragma unroll
  for (int it = 0; it < 8; ++it) {
    const int y = wv * 64 + it * 8 + ys;
    short8 k8 = *(const short8*)(Kb + (size_t)y * 64 + dc * 8);
    float s0 = 0.f, s1 = 0.f, s2 = 0.f, s3 = 0.f;
#pragma unroll
    for (int e = 0; e < 8; ++e) {
      float kv = b2f((u16)k8[e]);
      s0 += kv * qr[0][e]; s1 += kv * qr[1][e];
      s2 += kv * qr[2][e]; s3 += kv * qr[3][e];
    }
#pragma unroll
    for (int off = 1; off <= 4; off <<= 1) {
      s0 += __shfl_xor(s0, off); s1 += __shfl_xor(s1, off);
      s2 += __shfl_xor(s2, off); s3 += __shfl_xor(s3, off);
    }
    if (dc == 0) {
      sc[0][y] = s0; sc[1][y] = s1; sc[2][y] = s2; sc[3][y] = s3;
    }
  }
  __syncthreads();

  const int g = wv;
  const int pidx = (((bl * 12 + h) * 4 + g) * NSCH) + ch;
  {
    float m4 = fmaxf(fmaxf(sc[g][lane], sc[g][lane + 64]),
                     fmaxf(sc[g][lane + 128], sc[g][lane + 192]));
#pragma unroll
    for (int off = 32; off; off >>= 1) m4 = fmaxf(m4, __shfl_xor(m4, off));
    float ls = 0.f;
#pragma unroll
    for (int i = 0; i < 4; ++i) {
      int y = lane + i * 64;
      float p = __expf(sc[g][y] - m4);
      sc[g][y] = p;
      ls += p;
    }
#pragma unroll
    for (int off = 32; off; off >>= 1) ls += __shfl_xor(ls, off);
    if (lane == 0) { Mp[pidx] = m4; Lp[pidx] = ls; }
  }
  __syncthreads();

  {
    float o8[8] = {0.f, 0.f, 0.f, 0.f, 0.f, 0.f, 0.f, 0.f};
#pragma unroll 4
    for (int y0 = 0; y0 < CHUNK; y0 += 8) {
      float p = sc[g][y0 + ys];
      short8 v8 = *(const short8*)(Vb + (size_t)(y0 + ys) * 64 + dc * 8);
#pragma unroll
      for (int e = 0; e < 8; ++e) o8[e] += p * b2f((u16)v8[e]);
    }
#pragma unroll
    for (int off = 32; off >= 8; off >>= 1)
#pragma unroll
      for (int e = 0; e < 8; ++e) o8[e] += __shfl_xor(o8[e], off);
    if (ys == 0) {
      f32x4 lo, hi;
      lo.x = o8[0]; lo.y = o8[1]; lo.z = o8[2]; lo.w = o8[3];
      hi.x = o8[4]; hi.y = o8[5]; hi.z = o8[6]; hi.w = o8[7];
      *(f32x4*)(Op + (size_t)pidx * 64 + dc * 8) = lo;
      *(f32x4*)(Op + (size_t)pidx * 64 + dc * 8 + 4) = hi;
    }
  }
}

// ---------------------------------------------------------------------------
// K3b: combine chunk partials. grid = nb*48, block 64. (unchanged)
// ---------------------------------------------------------------------------
__global__ __launch_bounds__(64) void attn_combine(const float* __restrict__ Mp,
                                                   const float* __restrict__ Lp,
                                                   const float* __restrict__ Op,
                                                   float* __restrict__ Att,
                                                   int b0) {
  const int p = blockIdx.x;            // (bl*12+h)*4 + x
  const int d = threadIdx.x;
  const int x = p & 3;
  const int h = (p >> 2) % 12;
  const int bl = p / 48;

  float M = -__builtin_inff();
#pragma unroll 8
  for (int ch = 0; ch < NSCH; ++ch) M = fmaxf(M, Mp[p * NSCH + ch]);
  float L = 0.f, O = 0.f;
#pragma unroll 8
  for (int ch = 0; ch < NSCH; ++ch) {
    float w = __expf(Mp[p * NSCH + ch] - M);
    L += Lp[p * NSCH + ch] * w;
    O += Op[(size_t)(p * NSCH + ch) * 64 + d] * w;
  }
  Att[(size_t)((b0 + bl) * 4 + x) * 768 + h * 64 + d] = O / L;
}

// ---------------------------------------------------------------------------
// K4: output projection + bias, fp32 output. (unchanged)
// ---------------------------------------------------------------------------
__global__ __launch_bounds__(256) void out_proj(const float* __restrict__ Att,
                                               const float* __restrict__ Wo,
                                               const float* __restrict__ Bo,
                                               float* __restrict__ Out) {
  __shared__ float xs[768];
  const int bid = blockIdx.x;
  const int rrow = bid / 3, cg = bid % 3;
  const int t = threadIdx.x;
  if (t < 192) *(f32x4*)&xs[t * 4] = *(const f32x4*)(Att + (size_t)rrow * 768 + t * 4);
  __syncthreads();
  const int c = cg * 256 + t;
  const float* wrow = Wo + (size_t)c * 768;
  float acc = 0.f;
#pragma unroll 8
  for (int jj = 0; jj < 192; ++jj) {
    f32x4 v = *(const f32x4*)(wrow + jj * 4);
    acc += v.x * xs[jj * 4] + v.y * xs[jj * 4 + 1] + v.z * xs[jj * 4 + 2] +
           v.w * xs[jj * 4 + 3];
  }
  acc += Bo[c];
  Out[(size_t)rrow * 768 + c] = acc;
}

// ---------------------------------------------------------------------------
extern "C" void kernel_launch(void* const* d_in, const int* in_sizes, int n_in,
                              void* d_out, int out_size, void* d_ws, size_t ws_size,
                              hipStream_t stream) {
  const float* X = (const float*)d_in[0];    // [8,8192,768] fp32
  const float* Wkv = (const float*)d_in[1];  // [1536,768] fp32
  const float* Wq = (const float*)d_in[2];   // [768,768] fp32
  const float* Wo = (const float*)d_in[3];   // [768,768] fp32
  const float* Bo = (const float*)d_in[4];   // [768] fp32
  float* Out = (float*)d_out;                // [8,4,768] fp32

  char* ws = (char*)d_ws;
  size_t off = 0;
  float* Q = (float*)(ws + off); off += 98304;
  float* Att = (float*)(ws + off); off += 98304;
  float* Mp = (float*)(ws + off); off += 384 * NSCH * 4;
  float* Lp = (float*)(ws + off); off += 384 * NSCH * 4;
  float* Op = (float*)(ws + off); off += (size_t)384 * NSCH * 64 * 4;
  u16* Wbf = (u16*)(ws + off); off += 2359296;
  u16* Xbf = (u16*)(ws + off); off += 100663296ull;
  const size_t tail = off;
  const size_t kvPerBatch = 2ull * 12 * 8192 * 64 * 2;  // 25,165,824 B

  int nb = 8;
  while (nb > 1 && tail + (size_t)nb * kvPerBatch > ws_size) nb >>= 1;
  const int groups = 8 / nb;
  u16* KV = (u16*)(ws + tail);

  hipLaunchKernelGGL(cvt_bf16, dim3(576), dim3(256), 0, stream, Wkv, Wbf,
                     1536 * 768 / 8);
  hipLaunchKernelGGL(cvt_bf16, dim3(24576), dim3(256), 0, stream, X, Xbf,
                     8 * 8192 * 768 / 8);
  hipLaunchKernelGGL(q_proj, dim3(96), dim3(256), 0, stream, X, Wq, Q);

  for (int g = 0; g < groups; ++g) {
    const int b0 = g * nb;
    hipLaunchKernelGGL(kv_gemm_mfma, dim3(nb * 768), dim3(256), 0, stream,
                       Xbf + (size_t)b0 * 8192 * 768, Wbf, KV, nb);
    hipLaunchKernelGGL(attn_part, dim3(nb * 12 * NSCH), dim3(256), 0, stream,
                       KV, Q, Mp, Lp, Op, b0, nb);
    hipLaunchKernelGGL(attn_combine, dim3(nb * 48), dim3(64), 0, stream,
                       Mp, Lp, Op, Att, b0);
  }
  hipLaunchKernelGGL(out_proj, dim3(96), dim3(256), 0, stream, Att, Wo, Bo, Out);
}

// Round 6
// 590.590 us; speedup vs baseline: 1.0473x; 1.0473x over previous
//
#include <hip/hip_runtime.h>

typedef unsigned short u16;
typedef __attribute__((ext_vector_type(8))) short short8;
typedef __attribute__((ext_vector_type(4))) float f32x4;
typedef __attribute__((ext_vector_type(8))) __bf16 bf16x8;

__device__ __forceinline__ float b2f(u16 u) {
  unsigned int i = ((unsigned int)u) << 16;
  return __builtin_bit_cast(float, i);
}
__device__ __forceinline__ u16 f2b(float f) {
  unsigned int i = __builtin_bit_cast(unsigned int, f);
  i += 0x7fffu + ((i >> 16) & 1u);   // RNE
  return (u16)(i >> 16);
}

// ---------------------------------------------------------------------------
// K0: fp32 -> bf16 conversion. (unchanged)
// ---------------------------------------------------------------------------
__global__ __launch_bounds__(256) void cvt_bf16(const float* __restrict__ in,
                                                u16* __restrict__ out, int n8) {
  int i = blockIdx.x * 256 + threadIdx.x;
  if (i >= n8) return;
  f32x4 v0 = *(const f32x4*)(in + (size_t)i * 8);
  f32x4 v1 = *(const f32x4*)(in + (size_t)i * 8 + 4);
  short8 o;
  o[0] = (short)f2b(v0.x); o[1] = (short)f2b(v0.y);
  o[2] = (short)f2b(v0.z); o[3] = (short)f2b(v0.w);
  o[4] = (short)f2b(v1.x); o[5] = (short)f2b(v1.y);
  o[6] = (short)f2b(v1.z); o[7] = (short)f2b(v1.w);
  *(short8*)(out + (size_t)i * 8) = o;
}

// ---------------------------------------------------------------------------
// K1: KV projection, 256x256 8-phase schedule (T1+T2+T3+T4+T5).
// BM=BN=256, BK=64, 512 thr = 8 waves (2M x 4N). LDS = 2 tile-buffers x
// (A 32KB + B 32KB) = 128 KiB. Tile T lives in buf(T&1).
// Phase p of tile T: reads A-half(p>>1), B-half(p&1) only; stages ONE
// half-tile for a future tile (issued exactly one phase after the region's
// last read); barrier / lgkmcnt(0) / setprio(1) 16xMFMA setprio(0) / barrier.
// Counted vmcnt(4) at tile boundaries only (newest 2 half-tiles in flight).
// T2 swizzle: kbyte ^= (row&7)<<4, applied on pre-swizzled global source
// (linear global_load_lds dest) and on the ds_read address (involution).
// ---------------------------------------------------------------------------
#define NT 12   // 768 / 64 K-tiles

__global__ __launch_bounds__(512, 2) void kv_gemm_8ph(const u16* __restrict__ A,
                                                      const u16* __restrict__ B,
                                                      u16* __restrict__ KV, int nb) {
  __shared__ alignas(16) u16 lds[2][2][16384];  // [buf][op: 0=A 1=B][256*64]
  const int tid = threadIdx.x;
  const int lane = tid & 63;
  const int w = tid >> 6;                 // wave 0..7
  const int wm = w >> 2, wn = w & 3;      // 2M x 4N
  const int fr = lane & 15, fq = lane >> 4;

  // T1: bijective XCD swizzle (grid % 8 == 0 always).
  const int bid0 = blockIdx.x;
  const int cpx = gridDim.x >> 3;
  const int bid = (bid0 & 7) * cpx + (bid0 >> 3);
  const int nt = bid % 6, mt = bid / 6;
  const int m0 = mt * 256, n0 = nt * 256;

  // Stage one half-tile (16 KB): 512 thr x 2 rounds x 16 B. Linear LDS dest
  // (wave-uniform base + lane*16); source address pre-swizzled.
  auto stage = [&](int buf, int op, int hh, int ktile) {
    const u16* src = op ? B : A;
    const int r0 = op ? n0 : m0;
#pragma unroll
    for (int r = 0; r < 2; ++r) {
      int c = (r * 8 + w) * 64 + lane;            // phys 16B-chunk id
      int row = c >> 3;                           // 0..127
      int kb = ((c & 7) * 16) ^ ((row & 7) << 4); // logical k-byte (swizzle^-1)
      const u16* g = src + (size_t)(r0 + hh * 128 + row) * 768 + ktile * 64 + (kb >> 1);
      __builtin_amdgcn_global_load_lds(
          (const __attribute__((address_space(1))) void*)g,
          (__attribute__((address_space(3))) void*)(&lds[buf][op][hh * 8192 + (r * 8 + w) * 512]),
          16, 0, 0);
    }
  };

  f32x4 acc[2][2][4][2] = {};   // [ah][bh][m][n]; swapped-operand MFMA

  // Prologue: tile0 (4 halves) + tile1 (Ah0, Bh0); allow newest 2 halves out.
  stage(0, 0, 0, 0); stage(0, 1, 0, 0);
  stage(0, 0, 1, 0); stage(0, 1, 1, 0);
  stage(1, 0, 0, 1); stage(1, 1, 0, 1);
  asm volatile("s_waitcnt vmcnt(4)" ::: "memory");
  __builtin_amdgcn_sched_barrier(0);
  __builtin_amdgcn_s_barrier();

#pragma unroll 1
  for (int T = 0; T < NT; ++T) {
    const int buf = T & 1;
#pragma unroll
    for (int p = 0; p < 4; ++p) {
      const int ah = p >> 1, bh = p & 1;

      // ds-load register subtile: 8 A + 4 B ds_read_b128 (swizzled addr).
      bf16x8 af[4][2], bfr[2][2];
#pragma unroll
      for (int m = 0; m < 4; ++m)
#pragma unroll
        for (int ks = 0; ks < 2; ++ks) {
          int row = wm * 64 + m * 16 + fr;
          int kb = (ks * 64 + fq * 16) ^ ((fr & 7) << 4);
          af[m][ks] = *(const bf16x8*)((const char*)&lds[buf][0][0] +
                                       ah * 16384 + row * 128 + kb);
        }
#pragma unroll
      for (int n = 0; n < 2; ++n)
#pragma unroll
        for (int ks = 0; ks < 2; ++ks) {
          int row = wn * 32 + n * 16 + fr;
          int kb = (ks * 64 + fq * 16) ^ ((fr & 7) << 4);
          bfr[n][ks] = *(const bf16x8*)((const char*)&lds[buf][1][0] +
                                        bh * 16384 + row * 128 + kb);
        }

      // Stage exactly one future half-tile. Region liveness:
      //   p0: buf^1 Ah1(T+1)  (old Ah1 last read at (T-1).p3)
      //   p1: buf^1 Bh1(T+1)  (old Bh1 last read at (T-1).p3)
      //   p2: buf   Ah0(T+2)  (Ah0(T) last read at p1)
      //   p3: buf   Bh0(T+2)  (Bh0(T) last read at p2)
      if (p == 0)      { if (T + 1 < NT) stage(buf ^ 1, 0, 1, T + 1); }
      else if (p == 1) { if (T + 1 < NT) stage(buf ^ 1, 1, 1, T + 1); }
      else if (p == 2) { if (T + 2 < NT) stage(buf, 0, 0, T + 2); }
      else             { if (T + 2 < NT) stage(buf, 1, 0, T + 2); }

      __builtin_amdgcn_s_barrier();
      asm volatile("s_waitcnt lgkmcnt(0)" ::: "memory");
      __builtin_amdgcn_sched_barrier(0);

      __builtin_amdgcn_s_setprio(1);
#pragma unroll
      for (int m = 0; m < 4; ++m)
#pragma unroll
        for (int n = 0; n < 2; ++n)
#pragma unroll
          for (int ks = 0; ks < 2; ++ks)
            acc[ah][bh][m][n] = __builtin_amdgcn_mfma_f32_16x16x32_bf16(
                bfr[n][ks], af[m][ks], acc[ah][bh][m][n], 0, 0, 0);
      __builtin_amdgcn_s_setprio(0);

      if (p < 3) __builtin_amdgcn_s_barrier();
    }
    // Tile boundary: per-wave counted vmcnt, then collective barrier.
    if (T < NT - 1) {
      if (T < NT - 2) asm volatile("s_waitcnt vmcnt(4)" ::: "memory");
      else            asm volatile("s_waitcnt vmcnt(0)" ::: "memory");
      __builtin_amdgcn_sched_barrier(0);
      __builtin_amdgcn_s_barrier();
    }
  }

  // Epilogue: swapped layout -> D-row = feature (fq*4+j consecutive),
  // D-col = token (fr). Pack 4 bf16 -> 8B store.
  const int bl = m0 >> 13;
  const int sb = m0 & 8191;
#pragma unroll
  for (int bh = 0; bh < 2; ++bh)
#pragma unroll
    for (int n = 0; n < 2; ++n) {
      int f0 = n0 + bh * 128 + wn * 32 + n * 16 + fq * 4;
      int kvsel = f0 >= 768 ? 1 : 0;
      int h = (f0 >> 6) - kvsel * 12;
      int d0 = f0 & 63;
      u16* outp = KV + ((size_t)(kvsel * nb + bl) * 12 + h) * (8192 * 64) + d0;
#pragma unroll
      for (int ah = 0; ah < 2; ++ah)
#pragma unroll
        for (int m = 0; m < 4; ++m) {
          int s = sb + ah * 128 + wm * 64 + m * 16 + fr;
          union { u16 q[4]; unsigned long long u; } pk;
          pk.q[0] = f2b(acc[ah][bh][m][n][0]);
          pk.q[1] = f2b(acc[ah][bh][m][n][1]);
          pk.q[2] = f2b(acc[ah][bh][m][n][2]);
          pk.q[3] = f2b(acc[ah][bh][m][n][3]);
          *(unsigned long long*)(outp + (size_t)s * 64) = pk.u;
        }
    }
}

// ---------------------------------------------------------------------------
// K2: Q projection (fp32), scale 0.125 folded in. (unchanged)
// ---------------------------------------------------------------------------
__global__ __launch_bounds__(256) void q_proj(const float* __restrict__ X,
                                              const float* __restrict__ Wq,
                                              float* __restrict__ Q) {
  __shared__ float xs[768];
  const int bid = blockIdx.x;
  const int rrow = bid / 3, cg = bid % 3;
  const int b = rrow >> 2, s = rrow & 3;
  const float* xrow = X + ((size_t)b * 8192 + s) * 768;
  const int t = threadIdx.x;
  if (t < 192) *(f32x4*)&xs[t * 4] = *(const f32x4*)(xrow + t * 4);
  __syncthreads();
  const int c = cg * 256 + t;
  const float* wrow = Wq + (size_t)c * 768;
  float acc = 0.f;
#pragma unroll 8
  for (int jj = 0; jj < 192; ++jj) {
    f32x4 v = *(const f32x4*)(wrow + jj * 4);
    acc += v.x * xs[jj * 4] + v.y * xs[jj * 4 + 1] + v.z * xs[jj * 4 + 2] +
           v.w * xs[jj * 4 + 3];
  }
  Q[(size_t)rrow * 768 + c] = acc * 0.125f;
}

// ---------------------------------------------------------------------------
// K3a: split-S attention partials. (unchanged)
// ---------------------------------------------------------------------------
#define CHUNK 256
#define NSCH 32

__global__ __launch_bounds__(256) void attn_part(const u16* __restrict__ KV,
                                                 const float* __restrict__ Q,
                                                 float* __restrict__ Mp,
                                                 float* __restrict__ Lp,
                                                 float* __restrict__ Op,
                                                 int b0, int nb) {
  __shared__ float qsh[4][64];
  __shared__ float sc[4][CHUNK];
  const int tid = threadIdx.x;
  const int bid = blockIdx.x;
  const int ch = bid % NSCH;
  const int rem = bid / NSCH;
  const int h = rem % 12, bl = rem / 12;
  const int b = b0 + bl;

  qsh[tid >> 6][tid & 63] = Q[(size_t)(b * 4 + (tid >> 6)) * 768 + h * 64 + (tid & 63)];
  __syncthreads();

  const u16* Kb = KV + (size_t)(bl * 12 + h) * (8192 * 64) + (size_t)ch * CHUNK * 64;
  const u16* Vb = KV + (size_t)((nb + bl) * 12 + h) * (8192 * 64) + (size_t)ch * CHUNK * 64;

  const int wv = tid >> 6;
  const int lane = tid & 63;
  const int ys = lane >> 3, dc = lane & 7;

  float qr[4][8];
#pragma unroll
  for (int x = 0; x < 4; ++x) {
    f32x4 lo = *(const f32x4*)&qsh[x][dc * 8];
    f32x4 hi = *(const f32x4*)&qsh[x][dc * 8 + 4];
    qr[x][0] = lo.x; qr[x][1] = lo.y; qr[x][2] = lo.z; qr[x][3] = lo.w;
    qr[x][4] = hi.x; qr[x][5] = hi.y; qr[x][6] = hi.z; qr[x][7] = hi.w;
  }

#pragma unroll
  for (int it = 0; it < 8; ++it) {
    const int y = wv * 64 + it * 8 + ys;
    short8 k8 = *(const short8*)(Kb + (size_t)y * 64 + dc * 8);
    float s0 = 0.f, s1 = 0.f, s2 = 0.f, s3 = 0.f;
#pragma unroll
    for (int e = 0; e < 8; ++e) {
      float kv = b2f((u16)k8[e]);
      s0 += kv * qr[0][e]; s1 += kv * qr[1][e];
      s2 += kv * qr[2][e]; s3 += kv * qr[3][e];
    }
#pragma unroll
    for (int off = 1; off <= 4; off <<= 1) {
      s0 += __shfl_xor(s0, off); s1 += __shfl_xor(s1, off);
      s2 += __shfl_xor(s2, off); s3 += __shfl_xor(s3, off);
    }
    if (dc == 0) {
      sc[0][y] = s0; sc[1][y] = s1; sc[2][y] = s2; sc[3][y] = s3;
    }
  }
  __syncthreads();

  const int g = wv;
  const int pidx = (((bl * 12 + h) * 4 + g) * NSCH) + ch;
  {
    float m4 = fmaxf(fmaxf(sc[g][lane], sc[g][lane + 64]),
                     fmaxf(sc[g][lane + 128], sc[g][lane + 192]));
#pragma unroll
    for (int off = 32; off; off >>= 1) m4 = fmaxf(m4, __shfl_xor(m4, off));
    float ls = 0.f;
#pragma unroll
    for (int i = 0; i < 4; ++i) {
      int y = lane + i * 64;
      float p = __expf(sc[g][y] - m4);
      sc[g][y] = p;
      ls += p;
    }
#pragma unroll
    for (int off = 32; off; off >>= 1) ls += __shfl_xor(ls, off);
    if (lane == 0) { Mp[pidx] = m4; Lp[pidx] = ls; }
  }
  __syncthreads();

  {
    float o8[8] = {0.f, 0.f, 0.f, 0.f, 0.f, 0.f, 0.f, 0.f};
#pragma unroll 4
    for (int y0 = 0; y0 < CHUNK; y0 += 8) {
      float p = sc[g][y0 + ys];
      short8 v8 = *(const short8*)(Vb + (size_t)(y0 + ys) * 64 + dc * 8);
#pragma unroll
      for (int e = 0; e < 8; ++e) o8[e] += p * b2f((u16)v8[e]);
    }
#pragma unroll
    for (int off = 32; off >= 8; off >>= 1)
#pragma unroll
      for (int e = 0; e < 8; ++e) o8[e] += __shfl_xor(o8[e], off);
    if (ys == 0) {
      f32x4 lo, hi;
      lo.x = o8[0]; lo.y = o8[1]; lo.z = o8[2]; lo.w = o8[3];
      hi.x = o8[4]; hi.y = o8[5]; hi.z = o8[6]; hi.w = o8[7];
      *(f32x4*)(Op + (size_t)pidx * 64 + dc * 8) = lo;
      *(f32x4*)(Op + (size_t)pidx * 64 + dc * 8 + 4) = hi;
    }
  }
}

// ---------------------------------------------------------------------------
// K3b: combine chunk partials. (unchanged)
// ---------------------------------------------------------------------------
__global__ __launch_bounds__(64) void attn_combine(const float* __restrict__ Mp,
                                                   const float* __restrict__ Lp,
                                                   const float* __restrict__ Op,
                                                   float* __restrict__ Att,
                                                   int b0) {
  const int p = blockIdx.x;
  const int d = threadIdx.x;
  const int x = p & 3;
  const int h = (p >> 2) % 12;
  const int bl = p / 48;

  float M = -__builtin_inff();
#pragma unroll 8
  for (int ch = 0; ch < NSCH; ++ch) M = fmaxf(M, Mp[p * NSCH + ch]);
  float L = 0.f, O = 0.f;
#pragma unroll 8
  for (int ch = 0; ch < NSCH; ++ch) {
    float w = __expf(Mp[p * NSCH + ch] - M);
    L += Lp[p * NSCH + ch] * w;
    O += Op[(size_t)(p * NSCH + ch) * 64 + d] * w;
  }
  Att[(size_t)((b0 + bl) * 4 + x) * 768 + h * 64 + d] = O / L;
}

// ---------------------------------------------------------------------------
// K4: output projection + bias, fp32 output. (unchanged)
// ---------------------------------------------------------------------------
__global__ __launch_bounds__(256) void out_proj(const float* __restrict__ Att,
                                               const float* __restrict__ Wo,
                                               const float* __restrict__ Bo,
                                               float* __restrict__ Out) {
  __shared__ float xs[768];
  const int bid = blockIdx.x;
  const int rrow = bid / 3, cg = bid % 3;
  const int t = threadIdx.x;
  if (t < 192) *(f32x4*)&xs[t * 4] = *(const f32x4*)(Att + (size_t)rrow * 768 + t * 4);
  __syncthreads();
  const int c = cg * 256 + t;
  const float* wrow = Wo + (size_t)c * 768;
  float acc = 0.f;
#pragma unroll 8
  for (int jj = 0; jj < 192; ++jj) {
    f32x4 v = *(const f32x4*)(wrow + jj * 4);
    acc += v.x * xs[jj * 4] + v.y * xs[jj * 4 + 1] + v.z * xs[jj * 4 + 2] +
           v.w * xs[jj * 4 + 3];
  }
  acc += Bo[c];
  Out[(size_t)rrow * 768 + c] = acc;
}

// ---------------------------------------------------------------------------
extern "C" void kernel_launch(void* const* d_in, const int* in_sizes, int n_in,
                              void* d_out, int out_size, void* d_ws, size_t ws_size,
                              hipStream_t stream) {
  const float* X = (const float*)d_in[0];    // [8,8192,768] fp32
  const float* Wkv = (const float*)d_in[1];  // [1536,768] fp32
  const float* Wq = (const float*)d_in[2];   // [768,768] fp32
  const float* Wo = (const float*)d_in[3];   // [768,768] fp32
  const float* Bo = (const float*)d_in[4];   // [768] fp32
  float* Out = (float*)d_out;                // [8,4,768] fp32

  char* ws = (char*)d_ws;
  size_t off = 0;
  float* Q = (float*)(ws + off); off += 98304;
  float* Att = (float*)(ws + off); off += 98304;
  float* Mp = (float*)(ws + off); off += 384 * NSCH * 4;
  float* Lp = (float*)(ws + off); off += 384 * NSCH * 4;
  float* Op = (float*)(ws + off); off += (size_t)384 * NSCH * 64 * 4;
  u16* Wbf = (u16*)(ws + off); off += 2359296;
  u16* Xbf = (u16*)(ws + off); off += 100663296ull;
  const size_t tail = off;
  const size_t kvPerBatch = 2ull * 12 * 8192 * 64 * 2;  // 25,165,824 B

  int nb = 8;
  while (nb > 1 && tail + (size_t)nb * kvPerBatch > ws_size) nb >>= 1;
  const int groups = 8 / nb;
  u16* KV = (u16*)(ws + tail);

  hipLaunchKernelGGL(cvt_bf16, dim3(576), dim3(256), 0, stream, Wkv, Wbf,
                     1536 * 768 / 8);
  hipLaunchKernelGGL(cvt_bf16, dim3(24576), dim3(256), 0, stream, X, Xbf,
                     8 * 8192 * 768 / 8);
  hipLaunchKernelGGL(q_proj, dim3(96), dim3(256), 0, stream, X, Wq, Q);

  for (int g = 0; g < groups; ++g) {
    const int b0 = g * nb;
    hipLaunchKernelGGL(kv_gemm_8ph, dim3(nb * 192), dim3(512), 0, stream,
                       Xbf + (size_t)b0 * 8192 * 768, Wbf, KV, nb);
    hipLaunchKernelGGL(attn_part, dim3(nb * 12 * NSCH), dim3(256), 0, stream,
                       KV, Q, Mp, Lp, Op, b0, nb);
    hipLaunchKernelGGL(attn_combine, dim3(nb * 48), dim3(64), 0, stream,
                       Mp, Lp, Op, Att, b0);
  }
  hipLaunchKernelGGL(out_proj, dim3(96), dim3(256), 0, stream, Att, Wo, Bo, Out);
}